// Round 1
// baseline (172.523 us; speedup 1.0000x reference)
//
#include <hip/hip_runtime.h>

// CostConcatenation: out[b, d+48, h, w, :] = valid ? concat(left[b,h,w,:], right[b,h,w-d,:]) : 0
// Shapes: left/right [2,64,256,32] f32; out [2,96,64,256,64] f32 (805 MB).
// Pure streaming-write kernel; roofline = HBM write BW (~6.3 TB/s -> ~130us).

#define BB 2
#define D2 96
#define HH 64
#define WW 256
#define CC 32   // per-image channels; output has 2*CC = 64

// Output float4 count: BB*D2*HH*WW*(2*CC/4) = 2*96*64*256*16 = 50331648
#define TOTAL4 50331648

__global__ __launch_bounds__(256) void cost_concat_kernel(
    const float4* __restrict__ left4,
    const float4* __restrict__ right4,
    float4* __restrict__ out4)
{
    const int stride = gridDim.x * blockDim.x;
    for (int i = blockIdx.x * blockDim.x + threadIdx.x; i < TOTAL4; i += stride) {
        // i = ((((b*96 + dd)*64 + h)*256 + w)*16 + c4)
        const int c4 = i & 15;          // 16 float4 per output pixel (64 channels)
        int t = i >> 4;
        const int w = t & 255;  t >>= 8;
        const int h = t & 63;   t >>= 6;
        const int dd = t % D2;          // t <= 191, cheap
        const int b  = t / D2;
        const int d  = dd - 48;
        const int idx = w - d;          // right-image column
        const bool valid = (idx >= 0) & (idx < WW);

        float4 v = make_float4(0.f, 0.f, 0.f, 0.f);
        if (valid) {
            if (c4 < 8) {
                // left half: channels [c4*4 .. c4*4+3] of left[b,h,w]
                v = left4[((b * HH + h) * WW + w) * 8 + c4];
            } else {
                // right half: channels of right[b,h,idx]
                v = right4[((b * HH + h) * WW + idx) * 8 + (c4 - 8)];
            }
        }
        out4[i] = v;
    }
}

extern "C" void kernel_launch(void* const* d_in, const int* in_sizes, int n_in,
                              void* d_out, int out_size, void* d_ws, size_t ws_size,
                              hipStream_t stream) {
    const float4* left4  = (const float4*)d_in[0];
    const float4* right4 = (const float4*)d_in[1];
    float4* out4 = (float4*)d_out;

    // Memory-bound: cap grid at ~8 blocks/CU * 256 CUs, grid-stride the rest.
    const int block = 256;
    const int grid = 2048;
    cost_concat_kernel<<<grid, block, 0, stream>>>(left4, right4, out4);
}